// Round 1
// baseline (147.015 us; speedup 1.0000x reference)
//
#include <hip/hip_runtime.h>
#include <hip/hip_bf16.h>
#include <stdint.h>

#define NB 32
#define NC 12
#define NH 256
#define NW 256
#define NFC 96
#define NK1 48
#define NHW (NH*NW)
#define HPAD 104   // shorts per pixel-row in hidden LDS (208B: 16B-aligned, breaks pow2 stride)

typedef __attribute__((ext_vector_type(8))) short bf16x8;
typedef __attribute__((ext_vector_type(4))) float f32x4;

__device__ __forceinline__ short f2bf(float f) {
    // round-to-nearest-even f32 -> bf16
    uint32_t u = __builtin_bit_cast(uint32_t, f);
    u = (u + 0x7FFFu + ((u >> 16) & 1u)) >> 16;
    return (short)u;
}

// 3x3 stencil, circular: o[0]=ident, o[1]=sobel_x, o[2]=sobel_y, o[3]=laplacian
__device__ __forceinline__ void perc_ch(const float* __restrict__ xc,
                                        int hm, int hc, int hp,
                                        int wm, int wc, int wp,
                                        float o[4]) {
    const float* r0 = xc + (hm << 8);
    const float* r1 = xc + (hc << 8);
    const float* r2 = xc + (hp << 8);
    float a00 = r0[wm], a01 = r0[wc], a02 = r0[wp];
    float a10 = r1[wm], a11 = r1[wc], a12 = r1[wp];
    float a20 = r2[wm], a21 = r2[wc], a22 = r2[wp];
    o[0] = a11;
    o[1] = (a02 - a00) + 2.f*(a12 - a10) + (a22 - a20);
    o[2] = (a20 - a00) + 2.f*(a21 - a01) + (a22 - a02);
    o[3] = ((a00 + a02) + (a20 + a22)) + 2.f*((a01 + a10) + (a12 + a21)) - 12.f*a11;
}

__global__ __launch_bounds__(256) void nca_fused(
    const float* __restrict__ x, const float* __restrict__ w1,
    const float* __restrict__ b1, const float* __restrict__ w2,
    const float* __restrict__ rmask, float* __restrict__ out)
{
    __shared__ float w1s[NFC*NK1];
    __shared__ float w2s[NC*NFC];
    __shared__ float b1s[NFC];
    __shared__ short hid[4][16][HPAD];   // per-wave hiddenT scratch [pixel][ch]

    const int tid = threadIdx.x;
    for (int i = tid; i < NFC*NK1; i += 256) w1s[i] = w1[i];
    for (int i = tid; i < NC*NFC; i += 256) w2s[i] = w2[i];
    if (tid < NFC) b1s[tid] = b1[tid];
    __syncthreads();

    const int lane = tid & 63;
    const int wv   = tid >> 6;
    const int g    = lane >> 4;   // 16-lane group: K-slice for A/B, row-slice for D
    const int p    = lane & 15;   // pixel column (B/D), weight row (A)

    // ---- build resident weight fragments ----
    // GEMM1: A = w1 tile t rows [16t,16t+16), lane holds A[p][k=32s+8g+j]
    bf16x8 a1[6][2];
    #pragma unroll
    for (int t = 0; t < 6; ++t) {
        const int row = 16*t + p;
        #pragma unroll
        for (int s = 0; s < 2; ++s) {
            bf16x8 f;
            #pragma unroll
            for (int j = 0; j < 8; ++j) {
                const int k = 32*s + 8*g + j;
                f[j] = (k < NK1) ? f2bf(w1s[row*NK1 + k]) : (short)0;
            }
            a1[t][s] = f;
        }
    }
    // GEMM2: A = w2 padded to 16 rows, lane holds A[p][k=32s+8g+j]
    bf16x8 a2[3];
    #pragma unroll
    for (int s = 0; s < 3; ++s) {
        bf16x8 f;
        #pragma unroll
        for (int j = 0; j < 8; ++j) {
            const int k = 32*s + 8*g + j;
            f[j] = (p < NC) ? f2bf(w2s[p*NFC + k]) : (short)0;
        }
        a2[s] = f;
    }
    // bias for D rows 16t+4g+r
    float b1r[6][4];
    #pragma unroll
    for (int t = 0; t < 6; ++t)
        #pragma unroll
        for (int r = 0; r < 4; ++r)
            b1r[t][r] = b1s[16*t + 4*g + r];

    const int b  = blockIdx.x >> 5;
    const int h0 = (blockIdx.x & 31) * 8;

    const float* xb = x + (size_t)b * NC * NHW;
    const float* mb = rmask + (size_t)b * NHW;
    float* ob = out + (size_t)b * NC * NHW;

    short* hbuf = &hid[wv][0][0];

    for (int rr = 0; rr < 2; ++rr) {
        const int h  = h0 + 2*wv + rr;
        const int hm = (h - 1) & 255;
        const int hp = (h + 1) & 255;
        for (int grp = 0; grp < 16; ++grp) {
            const int wc = grp*16 + p;
            const int wm = (wc - 1) & 255;
            const int wp = (wc + 1) & 255;

            // ---- perception -> y B-fragments (lane holds y[k][p], k=8g+j (+32)) ----
            bf16x8 yf0;
            bf16x8 yf1 = (bf16x8)(short)0;
            {
                float o4[4];
                const float* xc = xb + (size_t)(2*g) * NHW;
                perc_ch(xc, hm, h, hp, wm, wc, wp, o4);
                yf0[0]=f2bf(o4[0]); yf0[1]=f2bf(o4[1]); yf0[2]=f2bf(o4[2]); yf0[3]=f2bf(o4[3]);
                perc_ch(xc + NHW, hm, h, hp, wm, wc, wp, o4);
                yf0[4]=f2bf(o4[0]); yf0[5]=f2bf(o4[1]); yf0[6]=f2bf(o4[2]); yf0[7]=f2bf(o4[3]);
            }
            if (g < 2) {   // k=32..47 -> channels 8..11 live on groups 0,1 only
                float o4[4];
                const float* xc = xb + (size_t)(8 + 2*g) * NHW;
                perc_ch(xc, hm, h, hp, wm, wc, wp, o4);
                yf1[0]=f2bf(o4[0]); yf1[1]=f2bf(o4[1]); yf1[2]=f2bf(o4[2]); yf1[3]=f2bf(o4[3]);
                perc_ch(xc + NHW, hm, h, hp, wm, wc, wp, o4);
                yf1[4]=f2bf(o4[0]); yf1[5]=f2bf(o4[1]); yf1[6]=f2bf(o4[2]); yf1[7]=f2bf(o4[3]);
            }

            // ---- GEMM1: hiddenT = w1 * yT, +bias, ReLU, stash to LDS [pixel][ch] ----
            #pragma unroll
            for (int t = 0; t < 6; ++t) {
                f32x4 acc = {0.f, 0.f, 0.f, 0.f};
                acc = __builtin_amdgcn_mfma_f32_16x16x32_bf16(a1[t][0], yf0, acc, 0, 0, 0);
                acc = __builtin_amdgcn_mfma_f32_16x16x32_bf16(a1[t][1], yf1, acc, 0, 0, 0);
                short4 hv;
                hv.x = f2bf(fmaxf(acc[0] + b1r[t][0], 0.f));
                hv.y = f2bf(fmaxf(acc[1] + b1r[t][1], 0.f));
                hv.z = f2bf(fmaxf(acc[2] + b1r[t][2], 0.f));
                hv.w = f2bf(fmaxf(acc[3] + b1r[t][3], 0.f));
                *reinterpret_cast<short4*>(&hbuf[p*HPAD + 16*t + 4*g]) = hv;
            }

            // ---- GEMM2: outT = w2 * hiddenT (B-frag read back: 8 contiguous ch) ----
            f32x4 acc2 = {0.f, 0.f, 0.f, 0.f};
            #pragma unroll
            for (int s = 0; s < 3; ++s) {
                bf16x8 bfr = *reinterpret_cast<const bf16x8*>(&hbuf[p*HPAD + 32*s + 8*g]);
                acc2 = __builtin_amdgcn_mfma_f32_16x16x32_bf16(a2[s], bfr, acc2, 0, 0, 0);
            }

            // ---- epilogue: out = x + upd * floor(rand+0.5) ----
            const float um = floorf(mb[(h << 8) + wc] + 0.5f);
            if (g < 3) {   // D rows 0..11 are real channels; rows 12..15 are pad
                #pragma unroll
                for (int r = 0; r < 4; ++r) {
                    const size_t idx = (size_t)(4*g + r) * NHW + (h << 8) + wc;
                    ob[idx] = xb[idx] + acc2[r] * um;
                }
            }
        }
    }
}

extern "C" void kernel_launch(void* const* d_in, const int* in_sizes, int n_in,
                              void* d_out, int out_size, void* d_ws, size_t ws_size,
                              hipStream_t stream) {
    const float* x  = (const float*)d_in[0];
    const float* w1 = (const float*)d_in[1];
    const float* b1 = (const float*)d_in[2];
    const float* w2 = (const float*)d_in[3];
    const float* rm = (const float*)d_in[4];
    float* out = (float*)d_out;
    nca_fused<<<dim3(NB * (NH / 8)), dim3(256), 0, stream>>>(x, w1, b1, w2, rm, out);
}

// Round 4
// 140.628 us; speedup vs baseline: 1.0454x; 1.0454x over previous
//
#include <hip/hip_runtime.h>
#include <stdint.h>

#define NC 12
#define NHW (256*256)

typedef __attribute__((ext_vector_type(8))) short bf16x8;
typedef __attribute__((ext_vector_type(4))) float f32x4;
typedef __attribute__((ext_vector_type(4))) uint32_t u32x4;

// pack two f32 -> u32 of 2 bf16 (RNE); native __bf16 casts, compiler fuses to v_cvt_pk_bf16_f32
__device__ __forceinline__ uint32_t pkbf(float lo, float hi) {
    const uint16_t lu = __builtin_bit_cast(uint16_t, (__bf16)lo);
    const uint16_t hu = __builtin_bit_cast(uint16_t, (__bf16)hi);
    return (uint32_t)lu | ((uint32_t)hu << 16);
}

// Fully register-resident fused NCA step. Both GEMMs use logical-K permutations
// (legal because A and B fragments apply the SAME bijection):
//   GEMM1 (w1[96x48]·yT):  slot(s,g,j): s=0 -> col 12g+j ; s=1,j<4 -> col 12g+8+j ; else 0
//   GEMM2 (w2[12x96]·hT):  slot(s2,g,j) -> col 32s2 + 16*(j>=4) + 4g + (j&3)
// With GEMM2's bijection, GEMM1's D regs (hidden ch 16t+4g+r, pixel p) ARE the
// B-fragments of GEMM2 — no LDS, no bpermute, no cross-lane exchange at all.
__global__ __launch_bounds__(256) void nca_fused3(
    const float* __restrict__ x, const float* __restrict__ w1,
    const float* __restrict__ b1, const float* __restrict__ w2,
    const float* __restrict__ rmask, float* __restrict__ out)
{
    const int tid  = threadIdx.x;
    const int lane = tid & 63;
    const int wv   = tid >> 6;
    const int g    = lane >> 4;   // 16-lane group
    const int p    = lane & 15;   // pixel col (B/D), weight row (A)
    const int c0   = 3 * g;       // this lane's first perception channel

    // ---- resident A fragments + bias (w1/w2/b1 stay L2-resident) ----
    bf16x8 a1[6][2];
    f32x4  biasv[6];
    #pragma unroll
    for (int t = 0; t < 6; ++t) {
        const int row = 16*t + p;
        const float4 fa = *reinterpret_cast<const float4*>(w1 + row*48 + 12*g + 0); // ch 3g   f0..3
        const float4 fb = *reinterpret_cast<const float4*>(w1 + row*48 + 12*g + 4); // ch 3g+1 f0..3
        const float4 fc = *reinterpret_cast<const float4*>(w1 + row*48 + 12*g + 8); // ch 3g+2 f0..3
        u32x4 ua = { pkbf(fa.x, fa.y), pkbf(fa.z, fa.w), pkbf(fb.x, fb.y), pkbf(fb.z, fb.w) };
        u32x4 ub = { pkbf(fc.x, fc.y), pkbf(fc.z, fc.w), 0u, 0u };
        a1[t][0] = __builtin_bit_cast(bf16x8, ua);
        a1[t][1] = __builtin_bit_cast(bf16x8, ub);
        biasv[t] = *reinterpret_cast<const f32x4*>(b1 + 16*t + 4*g);
    }
    bf16x8 a2[3];
    #pragma unroll
    for (int s = 0; s < 3; ++s) {
        u32x4 u = {0u, 0u, 0u, 0u};
        if (p < NC) {
            const float4 wa = *reinterpret_cast<const float4*>(w2 + p*96 + 32*s + 4*g);      // k: 32s+4g+0..3
            const float4 wb = *reinterpret_cast<const float4*>(w2 + p*96 + 32*s + 16 + 4*g); // k: 32s+16+4g+0..3
            u = (u32x4){ pkbf(wa.x, wa.y), pkbf(wa.z, wa.w), pkbf(wb.x, wb.y), pkbf(wb.z, wb.w) };
        }
        a2[s] = __builtin_bit_cast(bf16x8, u);
    }

    const int b  = blockIdx.x >> 5;
    const int h0 = (blockIdx.x & 31) * 8;
    const float* __restrict__ xb = x + (size_t)b * NC * NHW;
    const float* __restrict__ mb = rmask + (size_t)b * NHW;
    float* __restrict__ ob = out + (size_t)b * NC * NHW;

    for (int rr = 0; rr < 2; ++rr) {
        const int h  = h0 + 2*wv + rr;
        const int hm = (h - 1) & 255;
        const int hp = (h + 1) & 255;
        const int hrow = h << 8;
        int rb[3][3];   // element offsets of this lane's 3 channels x 3 stencil rows
        #pragma unroll
        for (int ci = 0; ci < 3; ++ci) {
            const int cb = (c0 + ci) * NHW;
            rb[ci][0] = cb + (hm << 8);
            rb[ci][1] = cb + hrow;
            rb[ci][2] = cb + (hp << 8);
        }

        auto body = [&](const int wc, const int dm, const int dp) {
            // ---- perception: 3 channels/lane, 27 loads (imm offsets in the middle grps) ----
            uint32_t y00, y01, y02, y03, y10, y11;
            #pragma unroll
            for (int ci = 0; ci < 3; ++ci) {
                const float* r0 = xb + rb[ci][0] + wc;
                const float* r1 = xb + rb[ci][1] + wc;
                const float* r2 = xb + rb[ci][2] + wc;
                const float v0 = r0[dm], v1 = r0[0], v2 = r0[dp];
                const float v3 = r1[dm], v4 = r1[0], v5 = r1[dp];
                const float v6 = r2[dm], v7 = r2[0], v8 = r2[dp];
                const float fsx = (v2 - v0) + 2.f*(v5 - v3) + (v8 - v6);
                const float fsy = (v6 - v0) + 2.f*(v7 - v1) + (v8 - v2);
                const float flp = ((v0 + v2) + (v6 + v8)) + 2.f*((v1 + v3) + (v5 + v7)) - 12.f*v4;
                const uint32_t lo = pkbf(v4, fsx);   // filt0=ident, filt1=sobel_x
                const uint32_t hi = pkbf(fsy, flp);  // filt2=sobel_xT, filt3=lap
                if (ci == 0)      { y00 = lo; y01 = hi; }
                else if (ci == 1) { y02 = lo; y03 = hi; }
                else              { y10 = lo; y11 = hi; }
            }
            const bf16x8 yf0 = __builtin_bit_cast(bf16x8, (u32x4){y00, y01, y02, y03});
            const bf16x8 yf1 = __builtin_bit_cast(bf16x8, (u32x4){y10, y11, 0u, 0u});

            // ---- GEMM1: bias via C-in, ReLU, pack pairs (lane (g,p): ch 16t+4g+0..3, pixel p) ----
            uint32_t pu[6][2];
            #pragma unroll
            for (int t = 0; t < 6; ++t) {
                f32x4 acc = biasv[t];
                acc = __builtin_amdgcn_mfma_f32_16x16x32_bf16(a1[t][0], yf0, acc, 0, 0, 0);
                acc = __builtin_amdgcn_mfma_f32_16x16x32_bf16(a1[t][1], yf1, acc, 0, 0, 0);
                pu[t][0] = pkbf(fmaxf(acc[0], 0.f), fmaxf(acc[1], 0.f));
                pu[t][1] = pkbf(fmaxf(acc[2], 0.f), fmaxf(acc[3], 0.f));
            }

            // ---- GEMM2: B-frags ARE the pu words under the chosen K-bijection ----
            f32x4 acc2 = {0.f, 0.f, 0.f, 0.f};
            #pragma unroll
            for (int s2 = 0; s2 < 3; ++s2) {
                const u32x4 fb2 = { pu[2*s2][0], pu[2*s2][1], pu[2*s2+1][0], pu[2*s2+1][1] };
                acc2 = __builtin_amdgcn_mfma_f32_16x16x32_bf16(a2[s2], __builtin_bit_cast(bf16x8, fb2), acc2, 0, 0, 0);
            }

            // ---- epilogue: out = x + upd * floor(rand + 0.5)  (x re-reads are L1 hits) ----
            const float um = floorf(mb[hrow + wc] + 0.5f);
            if (g < 3) {
                #pragma unroll
                for (int r = 0; r < 4; ++r) {
                    const int idx = (4*g + r) * NHW + hrow + wc;
                    ob[idx] = xb[idx] + acc2[r] * um;
                }
            }
        };

        body(p, (p == 0) ? 255 : -1, 1);          // grp 0: left wrap on lane p==0
        #pragma unroll 1
        for (int grp = 1; grp < 15; ++grp)
            body((grp << 4) + p, -1, 1);          // middle: pure immediate offsets
        body(240 + p, -1, (p == 15) ? -255 : 1);  // grp 15: right wrap on lane p==15
    }
}

extern "C" void kernel_launch(void* const* d_in, const int* in_sizes, int n_in,
                              void* d_out, int out_size, void* d_ws, size_t ws_size,
                              hipStream_t stream) {
    const float* x  = (const float*)d_in[0];
    const float* w1 = (const float*)d_in[1];
    const float* b1 = (const float*)d_in[2];
    const float* w2 = (const float*)d_in[3];
    const float* rm = (const float*)d_in[4];
    float* out = (float*)d_out;
    nca_fused3<<<dim3(32 * 32), dim3(256), 0, stream>>>(x, w1, b1, w2, rm, out);
}